// Round 17
// baseline (466.893 us; speedup 1.0000x reference)
//
#include <hip/hip_runtime.h>
#include <hip/hip_bf16.h>
#include <hip/hip_fp16.h>

#define N_NODES 50000
#define N_EDGES 800000
#define BUCKET 64     // per-dst edge capacity; deg ~ Poisson(16), P(>64) ~ 1e-18
#define EDGE_TB 3125  // (N_EDGES+255)/256
#define COPY_NB 196   // (N_NODES+255)/256
#define DST_PER_XCD 6250  // N_NODES / 8

// ---------- helpers ----------
__device__ __forceinline__ float rdlane(float v, int k) {
    return __uint_as_float(__builtin_amdgcn_readlane(__float_as_uint(v), k));
}
template <int CTRL>
__device__ __forceinline__ float dpp_addf(float v) {
    int x = __builtin_amdgcn_update_dpp(0, __float_as_int(v), CTRL, 0xF, 0xF, true);
    return v + __int_as_float(x);
}
#define DPP_QX1  0xB1   // quad_perm [1,0,3,2]
#define DPP_QX2  0x4E   // quad_perm [2,3,0,1]
#define DPP_HM   0x141  // row_half_mirror
#define DPP_RM   0x140  // row_mirror
#define DPP_ROR4 0x124  // row_ror:4
#define DPP_ROR8 0x128  // row_ror:8
__device__ __forceinline__ float dpp_sum16(float v) {
    v = dpp_addf<DPP_QX1>(v);
    v = dpp_addf<DPP_QX2>(v);
    v = dpp_addf<DPP_HM>(v);
    v = dpp_addf<DPP_RM>(v);
    return v;
}
__device__ __forceinline__ void bsum4(float& v0, float& v1, float& v2, float& v3) {
    #pragma unroll
    for (int m = 1; m < 64; m <<= 1) {
        v0 += __shfl_xor(v0, m);
        v1 += __shfl_xor(v1, m);
        v2 += __shfl_xor(v2, m);
        v3 += __shfl_xor(v3, m);
    }
}

// ---------- fused setup ----------
// Edge phase XCD-partitioned (r16). NEW: streaming reads (col/ea/row) use
// NON-TEMPORAL loads so they don't evict dirty bucket lines from the home
// XCD's L2 — r16 showed partial merging (WRITE 40MB vs 51 unpartitioned,
// ideal ~7): the 47MB read stream was flushing dirty lines early.
__global__ void k_setup(const float* __restrict__ x, unsigned* __restrict__ cntC,
                        float4* __restrict__ xcur,
                        const int* __restrict__ row, const int* __restrict__ col,
                        const float* __restrict__ ea, uint2* __restrict__ colEA,
                        const float* __restrict__ qw, const float* __restrict__ qb,
                        const float* __restrict__ kw, const float* __restrict__ kb,
                        const float* __restrict__ vw, const float* __restrict__ vb,
                        const float* __restrict__ ow,
                        const float* __restrict__ in_w, const float* __restrict__ in_b,
                        const float* __restrict__ rw1all, const float* __restrict__ rb1all,
                        const float* __restrict__ swall,
                        float* __restrict__ cst, float* __restrict__ cstV,
                        float* __restrict__ cstM) {
    int tid = threadIdx.x;
    int bid = blockIdx.x;
    if (bid < 8 * EDGE_TB) {
        int filt = bid & 7;
        int e = (bid >> 3) * 256 + tid;
        if (e < N_EDGES) {
            int c = __builtin_nontemporal_load(&col[e]);
            if (c / DST_PER_XCD == filt) {
                unsigned slot = atomicAdd(&cntC[c], 1u);
                float ex_ = __builtin_nontemporal_load(&ea[2 * e]);
                float ey_ = __builtin_nontemporal_load(&ea[2 * e + 1]);
                int r = __builtin_nontemporal_load(&row[e]);
                __half2 h2 = __floats2half2_rn(ex_, ey_);
                colEA[(size_t)c * BUCKET + slot] =
                    make_uint2(*reinterpret_cast<unsigned*>(&h2), (unsigned)r);
            }
        }
        return;
    }
    if (bid < 8 * EDGE_TB + COPY_NB) {
        int n = (bid - 8 * EDGE_TB) * 256 + tid;
        if (n < N_NODES) xcur[n] = ((const float4*)x)[n];
        return;
    }
    int pb = bid - (8 * EDGE_TB + COPY_NB);
    int m = tid;
    if (m >= 64) return;
    int d = m & 15;
    if (pb < 4) {
        int L = pb;
        const float* qwl = qw + L * 256; const float* kwl = kw + L * 256;
        const float* qbl = qb + L * 64;  const float* kbl = kb + L * 64;
        float qa[4], ka[4];
        #pragma unroll
        for (int a = 0; a < 4; a++) { qa[a] = qwl[a * 64 + m]; ka[a] = kwl[a * 64 + m]; }
        float qbm = qbl[m], kbm = kbl[m];
        float vals[25];
        int idx = 0;
        #pragma unroll
        for (int a = 0; a < 4; a++)
            #pragma unroll
            for (int b = 0; b < 4; b++) vals[idx++] = qa[a] * ka[b];
        #pragma unroll
        for (int a = 0; a < 4; a++) vals[idx++] = qa[a] * kbm;
        #pragma unroll
        for (int b = 0; b < 4; b++) vals[idx++] = qbm * ka[b];
        vals[24] = qbm * kbm;
        #pragma unroll
        for (int i = 0; i < 25; i++) {
            float v = vals[i];
            v += __shfl_xor(v, 1); v += __shfl_xor(v, 2);
            v += __shfl_xor(v, 4); v += __shfl_xor(v, 8);
            vals[i] = v;
        }
        if (d == 0) {
            float* out = cst + L * 128 + (m >> 4) * 32;
            #pragma unroll
            for (int i = 0; i < 25; i++) out[i] = vals[i] * 0.25f;
        }
    } else if (pb < 8) {
        int L = pb - 4;
        int h = m >> 4;
        const float* vwl = vw + L * 256;
        const float* vbl = vb + L * 64;
        float4 owv = ((const float4*)(ow + L * 256))[m];
        float vals[20];
        #pragma unroll
        for (int a = 0; a < 4; a++) {
            float v = vwl[a * 64 + m];
            vals[a * 4 + 0] = v * owv.x; vals[a * 4 + 1] = v * owv.y;
            vals[a * 4 + 2] = v * owv.z; vals[a * 4 + 3] = v * owv.w;
        }
        float b = vbl[m];
        vals[16] = b * owv.x; vals[17] = b * owv.y; vals[18] = b * owv.z; vals[19] = b * owv.w;
        #pragma unroll
        for (int i = 0; i < 20; i++) {
            float v = vals[i];
            v += __shfl_xor(v, 1); v += __shfl_xor(v, 2);
            v += __shfl_xor(v, 4); v += __shfl_xor(v, 8);
            vals[i] = v;
        }
        if (d == 0) {
            float* out = cstV + L * 128 + h * 32;
            #pragma unroll
            for (int i = 0; i < 20; i++) out[i] = vals[i];
        }
    } else {
        int L = pb - 8;
        const float* rw1 = rw1all + L * 66 * 64;
        const float* rb1 = rb1all + L * 64;
        const float* sw  = swall + L * 64 * 256;
        float* M = cstM + L * 384;
        float bacc = rb1[m];
        float w0 = 0.f, w1 = 0.f, w2 = 0.f, w3 = 0.f;
        for (int k = 0; k < 64; k++) {
            float r = rw1[k * 64 + m];
            bacc += in_b[k] * r;
            w0 += in_w[k] * r;
            w1 += in_w[64 + k] * r;
            w2 += in_w[128 + k] * r;
            w3 += in_w[192 + k] * r;
        }
        M[m * 4 + 0] = w0; M[m * 4 + 1] = w1; M[m * 4 + 2] = w2; M[m * 4 + 3] = w3;
        M[256 + m] = bacc;
        if (m < 16) {
            int a = m >> 2, o = m & 3;
            float sacc = 0.f;
            for (int k = 0; k < 64; k++) sacc += in_w[a * 64 + k] * sw[k * 256 + o];
            M[320 + m] = sacc;
        }
        if (m < 4) {
            float sacc = 0.f;
            for (int k = 0; k < 64; k++) sacc += in_b[k] * sw[k * 256 + m];
            M[336 + m] = sacc;
        }
    }
}

// ---------- per-layer ----------
// layers 1..3: finalize prev layer -> new xcur (r10 form)
__global__ void k61(const float* __restrict__ att16, const float* __restrict__ sumexpP,
                    const float4* __restrict__ x4b, const float* __restrict__ ob,
                    const float* __restrict__ g, const float* __restrict__ bb,
                    const float* __restrict__ resw, float4* __restrict__ xcur) {
    int tid = threadIdx.x;
    int wid = (blockIdx.x * blockDim.x + tid) >> 6;
    int lane = tid & 63;
    int n0 = wid * 4;
    if (n0 >= N_NODES) return;
    float4 zp = ((const float4*)sumexpP)[lane];
    bsum4(zp.x, zp.y, zp.z, zp.w);
    int hh = (lane & 15) >> 2;
    float z = (hh == 0) ? zp.x : (hh == 1) ? zp.y : (hh == 2) ? zp.z : zp.w;
    float ob0 = ob[0], ob1 = ob[1], ob2 = ob[2], ob3 = ob[3];
    float g0 = g[0], g1 = g[1], g2 = g[2], g3 = g[3];
    float bb0 = bb[0], bb1 = bb[1], bb2 = bb[2], bb3 = bb[3];
    float rw = resw[0];
    #pragma unroll
    for (int i = 0; i < 4; i++) {
        int n = n0 + i;
        float a = 0.f;
        if (n < N_NODES && lane < 16) a = att16[n * 16 + lane] / z;
        a = dpp_addf<DPP_ROR4>(a);
        a = dpp_addf<DPP_ROR8>(a);
        float y0 = rdlane(a, 0), y1 = rdlane(a, 1), y2 = rdlane(a, 2), y3 = rdlane(a, 3);
        if (n < N_NODES) {
            float4 x4v = x4b[n];
            y0 += ob0 + x4v.x; y1 += ob1 + x4v.y;
            y2 += ob2 + x4v.z; y3 += ob3 + x4v.w;
            float mu = 0.25f * (y0 + y1 + y2 + y3);
            float d0 = y0 - mu, d1 = y1 - mu, d2 = y2 - mu, d3 = y3 - mu;
            float var = 0.25f * (d0 * d0 + d1 * d1 + d2 * d2 + d3 * d3);
            float rs = rsqrtf(var + 1e-5f);
            float4 xold = xcur[n];
            float nn0 = d0 * rs * g0 + bb0 + xold.x * rw;
            float nn1 = d1 * rs * g1 + bb1 + xold.y * rw;
            float nn2 = d2 * rs * g2 + bb2 + xold.z * rw;
            float nn3 = d3 * rs * g3 + bb3 + xold.w * rw;
            if (lane == 0) xcur[n] = make_float4(nn0, nn1, nn2, nn3);
        }
    }
}

// msg-gather HYBRID (r15 form, measured winner): lane-parallel coalesced loads
// staged to wave-local LDS, channel-parallel compute (lane owns 4 channels).
__global__ void k23b(const unsigned* __restrict__ cntC, const uint2* __restrict__ colEA,
                     const float4* __restrict__ xcur, const float* __restrict__ rw1,
                     const float* __restrict__ rw2, const float* __restrict__ cstM,
                     const float* __restrict__ rb2, const float* __restrict__ sb,
                     float4* __restrict__ x4b, float* __restrict__ sumexpP) {
    __shared__ float s_rw2[64][4];
    __shared__ float s_weff[64][4];
    __shared__ float s_w1[128];
    __shared__ float s_beff[64];
    __shared__ float s_sw16[16];
    __shared__ float s_sbe[4];
    __shared__ float4 s_x[16][16];    // staged payloads per group
    __shared__ float2 s_e[16][16];    // staged ea per group
    int tid = threadIdx.x;
    { int r = tid >> 2, cc = tid & 3; s_rw2[r][cc] = rw2[r * 64 + cc]; s_weff[r][cc] = cstM[tid]; }
    if (tid < 128) s_w1[tid] = rw1[64 * 64 + tid];
    if (tid < 64) s_beff[tid] = cstM[256 + tid];
    if (tid < 16) s_sw16[tid] = cstM[320 + tid];
    if (tid < 4)  s_sbe[tid]  = cstM[336 + tid];
    if (blockIdx.x == 0) sumexpP[tid] = 0.f;
    __syncthreads();
    int l16 = tid & 15, grp = tid >> 4;
    // per-lane weights for fixed channels ch = l16*4 + j
    float wf[4][4], bfr[4], w1a[4], w1b[4], wr2r[4][4];
    #pragma unroll
    for (int j = 0; j < 4; j++) {
        int ch = l16 * 4 + j;
        #pragma unroll
        for (int a = 0; a < 4; a++) wf[j][a] = s_weff[ch][a];
        bfr[j] = s_beff[ch];
        w1a[j] = s_w1[ch];
        w1b[j] = s_w1[64 + ch];
        #pragma unroll
        for (int o = 0; o < 4; o++) wr2r[j][o] = s_rw2[ch][o];
    }
    int c = blockIdx.x * 16 + grp;        // 3125*16 = 50000 exact
    float4 xc = xcur[c];
    int cnt = (int)cntC[c];
    const uint2* rowE = colEA + (size_t)c * BUCKET;
    int items = cnt + 1;                  // item 0 = self loop (ea = 0)
    float a0 = 0.f, a1 = 0.f, a2 = 0.f, a3 = 0.f;
    for (int base = 0; base < items; base += 16) {
        int it = base + l16;
        float4 xr = make_float4(0.f, 0.f, 0.f, 0.f);
        float2 ef2 = make_float2(0.f, 0.f);
        if (it < items) {
            if (it == 0) {
                xr = xc;
            } else {
                uint2 er = rowE[it - 1];          // coalesced 8B/lane
                xr = xcur[er.y];                  // per-lane gather
                __half2 eh = *reinterpret_cast<const __half2*>(&er.x);
                ef2 = __half22float2(eh);
            }
        }
        s_x[grp][l16] = xr;                       // wave-local stage
        s_e[grp][l16] = ef2;
        int lim = items - base; if (lim > 16) lim = 16;
        for (int q = 0; q < lim; q++) {
            float4 xq = s_x[grp][q];              // broadcast within group
            float2 eq = s_e[grp][q];
            #pragma unroll
            for (int j = 0; j < 4; j++) {
                float tk = bfr[j] + xq.x * wf[j][0] + xq.y * wf[j][1]
                         + xq.z * wf[j][2] + xq.w * wf[j][3];
                float pre = tk + eq.x * w1a[j] + eq.y * w1b[j];
                float rr = fmaxf(pre, 0.f);
                a0 += rr * wr2r[j][0]; a1 += rr * wr2r[j][1];
                a2 += rr * wr2r[j][2]; a3 += rr * wr2r[j][3];
            }
        }
    }
    a0 = dpp_sum16(a0); a1 = dpp_sum16(a1); a2 = dpp_sum16(a2); a3 = dpp_sum16(a3);
    if (l16 == 0) {
        float idg = 1.f / (float)(cnt + 1);
        float b0 = xc.x * s_sw16[0] + xc.y * s_sw16[4] + xc.z * s_sw16[8]  + xc.w * s_sw16[12] + s_sbe[0];
        float b1 = xc.x * s_sw16[1] + xc.y * s_sw16[5] + xc.z * s_sw16[9]  + xc.w * s_sw16[13] + s_sbe[1];
        float b2 = xc.x * s_sw16[2] + xc.y * s_sw16[6] + xc.z * s_sw16[10] + xc.w * s_sw16[14] + s_sbe[2];
        float b3 = xc.x * s_sw16[3] + xc.y * s_sw16[7] + xc.z * s_sw16[11] + xc.w * s_sw16[15] + s_sbe[3];
        x4b[c] = make_float4(a0 * idg + b0 + rb2[0] + sb[0],
                             a1 * idg + b1 + rb2[1] + sb[1],
                             a2 * idg + b2 + rb2[2] + sb[2],
                             a3 * idg + b3 + rb2[3] + sb[3]);
    }
}

// attention gather, WAVE-PER-DST, lane = (item, head): item = lane>>2,
// head = lane&3. Quad = one item (x4b gather quad-uniform -> merged).
// Per-lane preamble = 1 head (was 4); item-reduction = 4 shfl_xor x 5 accs
// = 20 ops (was 80 DPP); 5-shfl redistribution feeds 16 output lanes.
__global__ void k5_att(const unsigned* __restrict__ cntC, const uint2* __restrict__ colEA,
                       const float4* __restrict__ x4b, const float* __restrict__ cst,
                       const float* __restrict__ cstV, float* __restrict__ att16,
                       float* __restrict__ sumexpP) {
    __shared__ float s_cst[128];
    __shared__ float s_cstV[128];
    __shared__ float zs[4][4];
    int tid = threadIdx.x;
    if (tid < 128) { s_cst[tid] = cst[tid]; s_cstV[tid] = cstV[tid]; }
    __syncthreads();
    int lane = tid & 63;
    int wv = tid >> 6;
    int c = (blockIdx.x * blockDim.x + tid) >> 6;   // wave per dst; 12500*4 = 50000 exact
    int h = lane & 3;        // this lane's head
    int itl = lane >> 2;     // this lane's item slot (0..15)
    float4 xc = x4b[c];
    const float* C = s_cst + h * 32;
    float g0 = xc.x * C[0]  + xc.y * C[1]  + xc.z * C[2]  + xc.w * C[3]  + C[16];
    float g1 = xc.x * C[4]  + xc.y * C[5]  + xc.z * C[6]  + xc.w * C[7]  + C[17];
    float g2 = xc.x * C[8]  + xc.y * C[9]  + xc.z * C[10] + xc.w * C[11] + C[18];
    float g3 = xc.x * C[12] + xc.y * C[13] + xc.z * C[14] + xc.w * C[15] + C[19];
    float base = C[20] * xc.x + C[21] * xc.y + C[22] * xc.z + C[23] * xc.w + C[24];
    int cnt = (int)cntC[c];
    const unsigned* rowY = (const unsigned*)(colEA + (size_t)c * BUCKET);  // src at odd u32
    float S0 = 0.f, S1 = 0.f, S2 = 0.f, S3 = 0.f, z = 0.f;
    for (int bb = 0; bb < cnt; bb += 16) {
        int it = bb + itl;
        bool act = it < cnt;
        float4 xr = make_float4(0.f, 0.f, 0.f, 0.f);
        if (act) xr = x4b[rowY[2 * it + 1]];       // quad-uniform address
        float s = xr.x * g0 + xr.y * g1 + xr.z * g2 + xr.w * g3 + base;
        float ex = __expf(s) * (act ? 1.f : 0.f);
        z += ex; S0 += ex * xr.x; S1 += ex * xr.y; S2 += ex * xr.z; S3 += ex * xr.w;
    }
    // reduce over item lanes (same head = stride-4 class): xor 4,8,16,32
    #pragma unroll
    for (int m = 4; m < 64; m <<= 1) {
        S0 += __shfl_xor(S0, m); S1 += __shfl_xor(S1, m);
        S2 += __shfl_xor(S2, m); S3 += __shfl_xor(S3, m);
        z  += __shfl_xor(z, m);
    }
    if (lane < 4) zs[wv][lane] = z;   // lane i holds head i's z
    // output lanes 0..15: h_out = lane>>2, a = lane&3; source lane h_out holds head h_out
    int ho = lane >> 2, a = lane & 3;
    float T0 = __shfl(S0, ho), T1 = __shfl(S1, ho);
    float T2 = __shfl(S2, ho), T3 = __shfl(S3, ho);
    float tz = __shfl(z, ho);
    if (lane < 16) {
        const float* V = s_cstV + ho * 32;
        float my = T0 * V[0 * 4 + a] + T1 * V[1 * 4 + a] + T2 * V[2 * 4 + a] + T3 * V[3 * 4 + a]
                 + tz * V[16 + a];
        att16[c * 16 + lane] = my;
    }
    __syncthreads();
    if (tid < 4) {
        float acc = zs[0][tid] + zs[1][tid] + zs[2][tid] + zs[3][tid];
        atomicAdd(&sumexpP[((blockIdx.x & 63) << 2) + tid], acc);
    }
}

// final: finalize layer 3 then MLP head (readlane GEMM) — unchanged
__global__ void k6pred(const float* __restrict__ att16, const float* __restrict__ sumexpP,
                       const float4* __restrict__ x4b, const float* __restrict__ ob,
                       const float* __restrict__ g, const float* __restrict__ bb,
                       const float* __restrict__ resw, const float4* __restrict__ xcur,
                       const float* __restrict__ in_w, const float* __restrict__ in_b,
                       const float* __restrict__ w1, const float* __restrict__ b1,
                       const float* __restrict__ w2, const float* __restrict__ b2,
                       float* __restrict__ out) {
    int tid = threadIdx.x;
    int node = (blockIdx.x * blockDim.x + tid) >> 6;
    int lane = tid & 63;
    if (node >= N_NODES) return;
    float4 zp = ((const float4*)sumexpP)[lane];
    bsum4(zp.x, zp.y, zp.z, zp.w);
    int hh = (lane & 15) >> 2;
    float z = (hh == 0) ? zp.x : (hh == 1) ? zp.y : (hh == 2) ? zp.z : zp.w;
    float a = 0.f;
    if (lane < 16) a = att16[node * 16 + lane] / z;
    a = dpp_addf<DPP_ROR4>(a);
    a = dpp_addf<DPP_ROR8>(a);
    float y0 = rdlane(a, 0), y1 = rdlane(a, 1), y2 = rdlane(a, 2), y3 = rdlane(a, 3);
    float4 x4v = x4b[node];
    y0 += ob[0] + x4v.x; y1 += ob[1] + x4v.y;
    y2 += ob[2] + x4v.z; y3 += ob[3] + x4v.w;
    float mu = 0.25f * (y0 + y1 + y2 + y3);
    float d0 = y0 - mu, d1 = y1 - mu, d2 = y2 - mu, d3 = y3 - mu;
    float var = 0.25f * (d0 * d0 + d1 * d1 + d2 * d2 + d3 * d3);
    float rs = rsqrtf(var + 1e-5f);
    float4 xold = xcur[node];
    float rw = resw[0];
    float n0 = d0 * rs * g[0] + bb[0] + xold.x * rw;
    float n1 = d1 * rs * g[1] + bb[1] + xold.y * rw;
    float n2 = d2 * rs * g[2] + bb[2] + xold.z * rw;
    float n3 = d3 * rs * g[3] + bb[3] + xold.w * rw;
    float hv = in_b[lane] + n0 * in_w[lane] + n1 * in_w[64 + lane]
             + n2 * in_w[128 + lane] + n3 * in_w[192 + lane];
    int j2 = lane & 31;
    float m = b1[j2];
    for (int k = 0; k < 64; k++) m += rdlane(hv, k) * w1[k * 32 + j2];
    m = fmaxf(m, 0.f);
    float4 w2v = ((const float4*)w2)[j2];
    float v0 = m * w2v.x, v1 = m * w2v.y, v2 = m * w2v.z, v3 = m * w2v.w;
    bsum4(v0, v1, v2, v3);  // each j2 counted twice (both halves) -> *0.5
    float o0 = tanhf(0.5f * v0 + b2[0]) * 0.3f;
    float o1 = tanhf(0.5f * v1 + b2[1]) * 0.3f;
    float o2 = tanhf(0.5f * v2 + b2[2]) * 0.3f;
    float o3 = tanhf(0.5f * v3 + b2[3]) * 0.3f;
    if (lane == 0) ((float4*)out)[node] = make_float4(o0, o1, o2, o3);
}

// ---------- launch ----------
extern "C" void kernel_launch(void* const* d_in, const int* in_sizes, int n_in,
                              void* d_out, int out_size, void* d_ws, size_t ws_size,
                              hipStream_t stream) {
    const float* x        = (const float*)d_in[0];
    const int*   ei       = (const int*)d_in[1];
    const float* ea       = (const float*)d_in[2];
    const float* in_w     = (const float*)d_in[3];
    const float* in_b     = (const float*)d_in[4];
    const float* conv_rw1 = (const float*)d_in[5];
    const float* conv_rb1 = (const float*)d_in[6];
    const float* conv_rw2 = (const float*)d_in[7];
    const float* conv_rb2 = (const float*)d_in[8];
    // d_in[9..12] (imag path) dead: x4 = h4[:, :4] only touches real[:, :4]
    const float* conv_sw  = (const float*)d_in[13];
    const float* conv_sb  = (const float*)d_in[14];
    const float* att_qw   = (const float*)d_in[15];
    const float* att_qb   = (const float*)d_in[16];
    const float* att_kw   = (const float*)d_in[17];
    const float* att_kb   = (const float*)d_in[18];
    const float* att_vw   = (const float*)d_in[19];
    const float* att_vb   = (const float*)d_in[20];
    const float* att_ow   = (const float*)d_in[21];
    const float* att_ob   = (const float*)d_in[22];
    const float* ln_g     = (const float*)d_in[23];
    const float* ln_b     = (const float*)d_in[24];
    const float* out_w1   = (const float*)d_in[25];
    const float* out_b1   = (const float*)d_in[26];
    const float* out_w2   = (const float*)d_in[27];
    const float* out_b2   = (const float*)d_in[28];
    const float* res_w    = (const float*)d_in[29];

    const int* row = ei;
    const int* col = ei + N_EDGES;

    char* ws = (char*)d_ws;
    size_t off = 0;
    auto alloc = [&](size_t bytes) -> void* {
        void* p = ws + off;
        off = (off + bytes + 255) & ~(size_t)255;
        return p;
    };
    unsigned* cntC     = (unsigned*)alloc(N_NODES * 4);
    uint2*    colEA    = (uint2*)alloc((size_t)N_NODES * BUCKET * 8);
    float*    att16    = (float*)alloc((size_t)N_NODES * 16 * 4);
    float4*   x4b      = (float4*)alloc((size_t)N_NODES * 16);
    float4*   xcur     = (float4*)alloc((size_t)N_NODES * 16);
    float*    cst      = (float*)alloc(4 * 128 * 4);
    float*    cstV     = (float*)alloc(4 * 128 * 4);
    float*    cstM     = (float*)alloc(4 * 384 * 4);  // per-layer Weff/beff/Sweff/sbe
    float*    sumexpP  = (float*)alloc(64 * 4 * 4);   // 64-way-split z partials

    dim3 b256(256);
    int grpBlocks   = (N_NODES + 15) / 16;      // 16 dsts per block (k23b)
    int attBlocks   = (N_NODES + 3) / 4;        // wave per dst (k5_att)
    int nodeBlocks4 = (N_NODES + 15) / 16;      // wave per 4 nodes (k61)

    hipMemsetAsync(cntC, 0, N_NODES * 4, stream);
    k_setup<<<8 * EDGE_TB + COPY_NB + 12, b256, 0, stream>>>(
        x, cntC, xcur, row, col, ea, colEA,
        att_qw, att_qb, att_kw, att_kb, att_vw, att_vb, att_ow,
        in_w, in_b, conv_rw1, conv_rb1, conv_sw,
        cst, cstV, cstM);

    for (int i = 0; i < 4; i++) {
        const float* rw1 = conv_rw1 + i * 66 * 64;
        const float* rw2 = conv_rw2 + i * 64 * 64;
        const float* rb2 = conv_rb2 + i * 64;
        const float* sbl = conv_sb + i * 256;

        if (i > 0) {
            k61<<<nodeBlocks4, b256, 0, stream>>>(att16, sumexpP, x4b,
                                                  att_ob + (i - 1) * 4, ln_g + (i - 1) * 4,
                                                  ln_b + (i - 1) * 4, res_w + (i - 1),
                                                  xcur);
        }
        k23b<<<grpBlocks, b256, 0, stream>>>(cntC, colEA, xcur, rw1, rw2,
                                             cstM + i * 384, rb2, sbl, x4b, sumexpP);
        k5_att<<<attBlocks, b256, 0, stream>>>(cntC, colEA, x4b, cst + i * 128,
                                               cstV + i * 128, att16, sumexpP);
    }
    k6pred<<<(N_NODES + 3) / 4, b256, 0, stream>>>(att16, sumexpP, x4b, att_ob + 12, ln_g + 12,
                                            ln_b + 12, res_w + 3, xcur, in_w, in_b,
                                            out_w1, out_b1, out_w2, out_b2, (float*)d_out);
}

// Round 18
// 397.637 us; speedup vs baseline: 1.1742x; 1.1742x over previous
//
#include <hip/hip_runtime.h>
#include <hip/hip_bf16.h>
#include <hip/hip_fp16.h>

#define N_NODES 50000
#define N_EDGES 800000
#define BUCKET 64     // per-dst edge capacity; deg ~ Poisson(16), P(>64) ~ 1e-18
#define EDGE_TB 3125  // (N_EDGES+255)/256
#define COPY_NB 196   // (N_NODES+255)/256
#define DST_PER_XCD 6250  // N_NODES / 8

// ---------- helpers ----------
__device__ __forceinline__ float rdlane(float v, int k) {
    return __uint_as_float(__builtin_amdgcn_readlane(__float_as_uint(v), k));
}
template <int CTRL>
__device__ __forceinline__ float dpp_addf(float v) {
    int x = __builtin_amdgcn_update_dpp(0, __float_as_int(v), CTRL, 0xF, 0xF, true);
    return v + __int_as_float(x);
}
#define DPP_QX1  0xB1   // quad_perm [1,0,3,2]
#define DPP_QX2  0x4E   // quad_perm [2,3,0,1]
#define DPP_HM   0x141  // row_half_mirror
#define DPP_RM   0x140  // row_mirror
#define DPP_ROR4 0x124  // row_ror:4
#define DPP_ROR8 0x128  // row_ror:8
__device__ __forceinline__ float dpp_sum16(float v) {
    v = dpp_addf<DPP_QX1>(v);
    v = dpp_addf<DPP_QX2>(v);
    v = dpp_addf<DPP_HM>(v);
    v = dpp_addf<DPP_RM>(v);
    return v;
}
__device__ __forceinline__ void bsum4(float& v0, float& v1, float& v2, float& v3) {
    #pragma unroll
    for (int m = 1; m < 64; m <<= 1) {
        v0 += __shfl_xor(v0, m);
        v1 += __shfl_xor(v1, m);
        v2 += __shfl_xor(v2, m);
        v3 += __shfl_xor(v3, m);
    }
}

// ---------- fused setup ----------
// Edge phase XCD-PARTITIONED (r16, measured 401.7): 8x EDGE_TB blocks; block
// bid handles only edges with dst range (bid&7) == col/6250. blockIdx
// round-robins XCDs, so all writers of a bucket line sit on ONE XCD -> its L2
// merges records and flushes once (WRITE 51.9 -> 40.4 MB measured). Regular
// cached loads (r17 NT-load A/B: WRITE -6MB but time neutral-negative).
__global__ void k_setup(const float* __restrict__ x, unsigned* __restrict__ cntC,
                        float4* __restrict__ xcur,
                        const int* __restrict__ row, const int* __restrict__ col,
                        const float* __restrict__ ea, uint2* __restrict__ colEA,
                        const float* __restrict__ qw, const float* __restrict__ qb,
                        const float* __restrict__ kw, const float* __restrict__ kb,
                        const float* __restrict__ vw, const float* __restrict__ vb,
                        const float* __restrict__ ow,
                        const float* __restrict__ in_w, const float* __restrict__ in_b,
                        const float* __restrict__ rw1all, const float* __restrict__ rb1all,
                        const float* __restrict__ swall,
                        float* __restrict__ cst, float* __restrict__ cstV,
                        float* __restrict__ cstM) {
    int tid = threadIdx.x;
    int bid = blockIdx.x;
    if (bid < 8 * EDGE_TB) {
        int filt = bid & 7;
        int e = (bid >> 3) * 256 + tid;
        if (e < N_EDGES) {
            int c = col[e];
            if (c / DST_PER_XCD == filt) {
                unsigned slot = atomicAdd(&cntC[c], 1u);
                float2 e2 = ((const float2*)ea)[e];
                __half2 h2 = __floats2half2_rn(e2.x, e2.y);
                colEA[(size_t)c * BUCKET + slot] =
                    make_uint2(*reinterpret_cast<unsigned*>(&h2), (unsigned)row[e]);
            }
        }
        return;
    }
    if (bid < 8 * EDGE_TB + COPY_NB) {
        int n = (bid - 8 * EDGE_TB) * 256 + tid;
        if (n < N_NODES) xcur[n] = ((const float4*)x)[n];
        return;
    }
    int pb = bid - (8 * EDGE_TB + COPY_NB);
    int m = tid;
    if (m >= 64) return;
    int d = m & 15;
    if (pb < 4) {
        int L = pb;
        const float* qwl = qw + L * 256; const float* kwl = kw + L * 256;
        const float* qbl = qb + L * 64;  const float* kbl = kb + L * 64;
        float qa[4], ka[4];
        #pragma unroll
        for (int a = 0; a < 4; a++) { qa[a] = qwl[a * 64 + m]; ka[a] = kwl[a * 64 + m]; }
        float qbm = qbl[m], kbm = kbl[m];
        float vals[25];
        int idx = 0;
        #pragma unroll
        for (int a = 0; a < 4; a++)
            #pragma unroll
            for (int b = 0; b < 4; b++) vals[idx++] = qa[a] * ka[b];
        #pragma unroll
        for (int a = 0; a < 4; a++) vals[idx++] = qa[a] * kbm;
        #pragma unroll
        for (int b = 0; b < 4; b++) vals[idx++] = qbm * ka[b];
        vals[24] = qbm * kbm;
        #pragma unroll
        for (int i = 0; i < 25; i++) {
            float v = vals[i];
            v += __shfl_xor(v, 1); v += __shfl_xor(v, 2);
            v += __shfl_xor(v, 4); v += __shfl_xor(v, 8);
            vals[i] = v;
        }
        if (d == 0) {
            float* out = cst + L * 128 + (m >> 4) * 32;
            #pragma unroll
            for (int i = 0; i < 25; i++) out[i] = vals[i] * 0.25f;
        }
    } else if (pb < 8) {
        int L = pb - 4;
        int h = m >> 4;
        const float* vwl = vw + L * 256;
        const float* vbl = vb + L * 64;
        float4 owv = ((const float4*)(ow + L * 256))[m];
        float vals[20];
        #pragma unroll
        for (int a = 0; a < 4; a++) {
            float v = vwl[a * 64 + m];
            vals[a * 4 + 0] = v * owv.x; vals[a * 4 + 1] = v * owv.y;
            vals[a * 4 + 2] = v * owv.z; vals[a * 4 + 3] = v * owv.w;
        }
        float b = vbl[m];
        vals[16] = b * owv.x; vals[17] = b * owv.y; vals[18] = b * owv.z; vals[19] = b * owv.w;
        #pragma unroll
        for (int i = 0; i < 20; i++) {
            float v = vals[i];
            v += __shfl_xor(v, 1); v += __shfl_xor(v, 2);
            v += __shfl_xor(v, 4); v += __shfl_xor(v, 8);
            vals[i] = v;
        }
        if (d == 0) {
            float* out = cstV + L * 128 + h * 32;
            #pragma unroll
            for (int i = 0; i < 20; i++) out[i] = vals[i];
        }
    } else {
        int L = pb - 8;
        const float* rw1 = rw1all + L * 66 * 64;
        const float* rb1 = rb1all + L * 64;
        const float* sw  = swall + L * 64 * 256;
        float* M = cstM + L * 384;
        float bacc = rb1[m];
        float w0 = 0.f, w1 = 0.f, w2 = 0.f, w3 = 0.f;
        for (int k = 0; k < 64; k++) {
            float r = rw1[k * 64 + m];
            bacc += in_b[k] * r;
            w0 += in_w[k] * r;
            w1 += in_w[64 + k] * r;
            w2 += in_w[128 + k] * r;
            w3 += in_w[192 + k] * r;
        }
        M[m * 4 + 0] = w0; M[m * 4 + 1] = w1; M[m * 4 + 2] = w2; M[m * 4 + 3] = w3;
        M[256 + m] = bacc;
        if (m < 16) {
            int a = m >> 2, o = m & 3;
            float sacc = 0.f;
            for (int k = 0; k < 64; k++) sacc += in_w[a * 64 + k] * sw[k * 256 + o];
            M[320 + m] = sacc;
        }
        if (m < 4) {
            float sacc = 0.f;
            for (int k = 0; k < 64; k++) sacc += in_b[k] * sw[k * 256 + m];
            M[336 + m] = sacc;
        }
    }
}

// ---------- per-layer ----------
// layers 1..3: finalize prev layer -> new xcur (r10 form)
__global__ void k61(const float* __restrict__ att16, const float* __restrict__ sumexpP,
                    const float4* __restrict__ x4b, const float* __restrict__ ob,
                    const float* __restrict__ g, const float* __restrict__ bb,
                    const float* __restrict__ resw, float4* __restrict__ xcur) {
    int tid = threadIdx.x;
    int wid = (blockIdx.x * blockDim.x + tid) >> 6;
    int lane = tid & 63;
    int n0 = wid * 4;
    if (n0 >= N_NODES) return;
    float4 zp = ((const float4*)sumexpP)[lane];
    bsum4(zp.x, zp.y, zp.z, zp.w);
    int hh = (lane & 15) >> 2;
    float z = (hh == 0) ? zp.x : (hh == 1) ? zp.y : (hh == 2) ? zp.z : zp.w;
    float ob0 = ob[0], ob1 = ob[1], ob2 = ob[2], ob3 = ob[3];
    float g0 = g[0], g1 = g[1], g2 = g[2], g3 = g[3];
    float bb0 = bb[0], bb1 = bb[1], bb2 = bb[2], bb3 = bb[3];
    float rw = resw[0];
    #pragma unroll
    for (int i = 0; i < 4; i++) {
        int n = n0 + i;
        float a = 0.f;
        if (n < N_NODES && lane < 16) a = att16[n * 16 + lane] / z;
        a = dpp_addf<DPP_ROR4>(a);
        a = dpp_addf<DPP_ROR8>(a);
        float y0 = rdlane(a, 0), y1 = rdlane(a, 1), y2 = rdlane(a, 2), y3 = rdlane(a, 3);
        if (n < N_NODES) {
            float4 x4v = x4b[n];
            y0 += ob0 + x4v.x; y1 += ob1 + x4v.y;
            y2 += ob2 + x4v.z; y3 += ob3 + x4v.w;
            float mu = 0.25f * (y0 + y1 + y2 + y3);
            float d0 = y0 - mu, d1 = y1 - mu, d2 = y2 - mu, d3 = y3 - mu;
            float var = 0.25f * (d0 * d0 + d1 * d1 + d2 * d2 + d3 * d3);
            float rs = rsqrtf(var + 1e-5f);
            float4 xold = xcur[n];
            float nn0 = d0 * rs * g0 + bb0 + xold.x * rw;
            float nn1 = d1 * rs * g1 + bb1 + xold.y * rw;
            float nn2 = d2 * rs * g2 + bb2 + xold.z * rw;
            float nn3 = d3 * rs * g3 + bb3 + xold.w * rw;
            if (lane == 0) xcur[n] = make_float4(nn0, nn1, nn2, nn3);
        }
    }
}

// msg-gather HYBRID (r15 form, measured winner): lane-parallel coalesced loads
// staged to wave-local LDS, channel-parallel compute (lane owns 4 channels).
__global__ void k23b(const unsigned* __restrict__ cntC, const uint2* __restrict__ colEA,
                     const float4* __restrict__ xcur, const float* __restrict__ rw1,
                     const float* __restrict__ rw2, const float* __restrict__ cstM,
                     const float* __restrict__ rb2, const float* __restrict__ sb,
                     float4* __restrict__ x4b, float* __restrict__ sumexpP) {
    __shared__ float s_rw2[64][4];
    __shared__ float s_weff[64][4];
    __shared__ float s_w1[128];
    __shared__ float s_beff[64];
    __shared__ float s_sw16[16];
    __shared__ float s_sbe[4];
    __shared__ float4 s_x[16][16];    // staged payloads per group
    __shared__ float2 s_e[16][16];    // staged ea per group
    int tid = threadIdx.x;
    { int r = tid >> 2, cc = tid & 3; s_rw2[r][cc] = rw2[r * 64 + cc]; s_weff[r][cc] = cstM[tid]; }
    if (tid < 128) s_w1[tid] = rw1[64 * 64 + tid];
    if (tid < 64) s_beff[tid] = cstM[256 + tid];
    if (tid < 16) s_sw16[tid] = cstM[320 + tid];
    if (tid < 4)  s_sbe[tid]  = cstM[336 + tid];
    if (blockIdx.x == 0) sumexpP[tid] = 0.f;
    __syncthreads();
    int l16 = tid & 15, grp = tid >> 4;
    // per-lane weights for fixed channels ch = l16*4 + j
    float wf[4][4], bfr[4], w1a[4], w1b[4], wr2r[4][4];
    #pragma unroll
    for (int j = 0; j < 4; j++) {
        int ch = l16 * 4 + j;
        #pragma unroll
        for (int a = 0; a < 4; a++) wf[j][a] = s_weff[ch][a];
        bfr[j] = s_beff[ch];
        w1a[j] = s_w1[ch];
        w1b[j] = s_w1[64 + ch];
        #pragma unroll
        for (int o = 0; o < 4; o++) wr2r[j][o] = s_rw2[ch][o];
    }
    int c = blockIdx.x * 16 + grp;        // 3125*16 = 50000 exact
    float4 xc = xcur[c];
    int cnt = (int)cntC[c];
    const uint2* rowE = colEA + (size_t)c * BUCKET;
    int items = cnt + 1;                  // item 0 = self loop (ea = 0)
    float a0 = 0.f, a1 = 0.f, a2 = 0.f, a3 = 0.f;
    for (int base = 0; base < items; base += 16) {
        int it = base + l16;
        float4 xr = make_float4(0.f, 0.f, 0.f, 0.f);
        float2 ef2 = make_float2(0.f, 0.f);
        if (it < items) {
            if (it == 0) {
                xr = xc;
            } else {
                uint2 er = rowE[it - 1];          // coalesced 8B/lane
                xr = xcur[er.y];                  // per-lane gather
                __half2 eh = *reinterpret_cast<const __half2*>(&er.x);
                ef2 = __half22float2(eh);
            }
        }
        s_x[grp][l16] = xr;                       // wave-local stage
        s_e[grp][l16] = ef2;
        int lim = items - base; if (lim > 16) lim = 16;
        for (int q = 0; q < lim; q++) {
            float4 xq = s_x[grp][q];              // broadcast within group
            float2 eq = s_e[grp][q];
            #pragma unroll
            for (int j = 0; j < 4; j++) {
                float tk = bfr[j] + xq.x * wf[j][0] + xq.y * wf[j][1]
                         + xq.z * wf[j][2] + xq.w * wf[j][3];
                float pre = tk + eq.x * w1a[j] + eq.y * w1b[j];
                float rr = fmaxf(pre, 0.f);
                a0 += rr * wr2r[j][0]; a1 += rr * wr2r[j][1];
                a2 += rr * wr2r[j][2]; a3 += rr * wr2r[j][3];
            }
        }
    }
    a0 = dpp_sum16(a0); a1 = dpp_sum16(a1); a2 = dpp_sum16(a2); a3 = dpp_sum16(a3);
    if (l16 == 0) {
        float idg = 1.f / (float)(cnt + 1);
        float b0 = xc.x * s_sw16[0] + xc.y * s_sw16[4] + xc.z * s_sw16[8]  + xc.w * s_sw16[12] + s_sbe[0];
        float b1 = xc.x * s_sw16[1] + xc.y * s_sw16[5] + xc.z * s_sw16[9]  + xc.w * s_sw16[13] + s_sbe[1];
        float b2 = xc.x * s_sw16[2] + xc.y * s_sw16[6] + xc.z * s_sw16[10] + xc.w * s_sw16[14] + s_sbe[2];
        float b3 = xc.x * s_sw16[3] + xc.y * s_sw16[7] + xc.z * s_sw16[11] + xc.w * s_sw16[15] + s_sbe[3];
        x4b[c] = make_float4(a0 * idg + b0 + rb2[0] + sb[0],
                             a1 * idg + b1 + rb2[1] + sb[1],
                             a2 * idg + b2 + rb2[2] + sb[2],
                             a3 * idg + b3 + rb2[3] + sb[3]);
    }
}

// attention gather, LANE-PARALLEL (r14 form, measured winner): 16-lane group
// per dst, lane = slot; DPP reductions (DPP = VALU-path, cheaper than shfl/DS
// — r17's shfl-based wave-per-dst variant cost +16us/layer).
__global__ void k5_att(const unsigned* __restrict__ cntC, const uint2* __restrict__ colEA,
                       const float4* __restrict__ x4b, const float* __restrict__ cst,
                       const float* __restrict__ cstV, float* __restrict__ att16,
                       float* __restrict__ sumexpP) {
    __shared__ float s_cst[128];
    __shared__ float s_cstV[128];
    __shared__ float zs[16][4];
    int tid = threadIdx.x;
    if (tid < 128) { s_cst[tid] = cst[tid]; s_cstV[tid] = cstV[tid]; }
    __syncthreads();
    int l16 = tid & 15, grp = tid >> 4;
    int c = blockIdx.x * 16 + grp;        // 3125*16 = 50000 exact
    float4 xc = x4b[c];
    float gh[4][4], bh[4];
    #pragma unroll
    for (int h = 0; h < 4; h++) {
        const float* C = s_cst + h * 32;
        gh[h][0] = xc.x * C[0]  + xc.y * C[1]  + xc.z * C[2]  + xc.w * C[3]  + C[16];
        gh[h][1] = xc.x * C[4]  + xc.y * C[5]  + xc.z * C[6]  + xc.w * C[7]  + C[17];
        gh[h][2] = xc.x * C[8]  + xc.y * C[9]  + xc.z * C[10] + xc.w * C[11] + C[18];
        gh[h][3] = xc.x * C[12] + xc.y * C[13] + xc.z * C[14] + xc.w * C[15] + C[19];
        bh[h]    = C[20] * xc.x + C[21] * xc.y + C[22] * xc.z + C[23] * xc.w + C[24];
    }
    int cnt = (int)cntC[c];
    const unsigned* rowY = (const unsigned*)(colEA + (size_t)c * BUCKET);  // src at odd u32
    float S00 = 0.f, S01 = 0.f, S02 = 0.f, S03 = 0.f;
    float S10 = 0.f, S11 = 0.f, S12 = 0.f, S13 = 0.f;
    float S20 = 0.f, S21 = 0.f, S22 = 0.f, S23 = 0.f;
    float S30 = 0.f, S31 = 0.f, S32 = 0.f, S33 = 0.f;
    float z0 = 0.f, z1 = 0.f, z2 = 0.f, z3 = 0.f;
    for (int base = 0; base < cnt; base += 16) {
        int it = base + l16;
        bool act = it < cnt;
        float4 xr = make_float4(0.f, 0.f, 0.f, 0.f);
        if (act) xr = x4b[rowY[2 * it + 1]];
        float actf = act ? 1.f : 0.f;
        {
            float s = xr.x * gh[0][0] + xr.y * gh[0][1] + xr.z * gh[0][2] + xr.w * gh[0][3] + bh[0];
            float ex = __expf(s) * actf;
            z0 += ex; S00 += ex * xr.x; S01 += ex * xr.y; S02 += ex * xr.z; S03 += ex * xr.w;
        }
        {
            float s = xr.x * gh[1][0] + xr.y * gh[1][1] + xr.z * gh[1][2] + xr.w * gh[1][3] + bh[1];
            float ex = __expf(s) * actf;
            z1 += ex; S10 += ex * xr.x; S11 += ex * xr.y; S12 += ex * xr.z; S13 += ex * xr.w;
        }
        {
            float s = xr.x * gh[2][0] + xr.y * gh[2][1] + xr.z * gh[2][2] + xr.w * gh[2][3] + bh[2];
            float ex = __expf(s) * actf;
            z2 += ex; S20 += ex * xr.x; S21 += ex * xr.y; S22 += ex * xr.z; S23 += ex * xr.w;
        }
        {
            float s = xr.x * gh[3][0] + xr.y * gh[3][1] + xr.z * gh[3][2] + xr.w * gh[3][3] + bh[3];
            float ex = __expf(s) * actf;
            z3 += ex; S30 += ex * xr.x; S31 += ex * xr.y; S32 += ex * xr.z; S33 += ex * xr.w;
        }
    }
    S00 = dpp_sum16(S00); S01 = dpp_sum16(S01); S02 = dpp_sum16(S02); S03 = dpp_sum16(S03);
    S10 = dpp_sum16(S10); S11 = dpp_sum16(S11); S12 = dpp_sum16(S12); S13 = dpp_sum16(S13);
    S20 = dpp_sum16(S20); S21 = dpp_sum16(S21); S22 = dpp_sum16(S22); S23 = dpp_sum16(S23);
    S30 = dpp_sum16(S30); S31 = dpp_sum16(S31); S32 = dpp_sum16(S32); S33 = dpp_sum16(S33);
    z0 = dpp_sum16(z0); z1 = dpp_sum16(z1); z2 = dpp_sum16(z2); z3 = dpp_sum16(z3);
    int h = l16 >> 2, a = l16 & 3;
    float Sa0 = (h == 0) ? S00 : (h == 1) ? S10 : (h == 2) ? S20 : S30;
    float Sa1 = (h == 0) ? S01 : (h == 1) ? S11 : (h == 2) ? S21 : S31;
    float Sa2 = (h == 0) ? S02 : (h == 1) ? S12 : (h == 2) ? S22 : S32;
    float Sa3 = (h == 0) ? S03 : (h == 1) ? S13 : (h == 2) ? S23 : S33;
    float zh  = (h == 0) ? z0  : (h == 1) ? z1  : (h == 2) ? z2  : z3;
    const float* V = s_cstV + h * 32;
    float my = Sa0 * V[0 * 4 + a] + Sa1 * V[1 * 4 + a] + Sa2 * V[2 * 4 + a] + Sa3 * V[3 * 4 + a]
             + zh * V[16 + a];
    att16[c * 16 + l16] = my;
    if (a == 0) zs[grp][h] = zh;
    __syncthreads();
    if (tid < 4) {
        float acc = 0.f;
        #pragma unroll
        for (int q = 0; q < 16; q++) acc += zs[q][tid];
        atomicAdd(&sumexpP[((blockIdx.x & 63) << 2) + tid], acc);
    }
}

// final: finalize layer 3 then MLP head (readlane GEMM) — unchanged
__global__ void k6pred(const float* __restrict__ att16, const float* __restrict__ sumexpP,
                       const float4* __restrict__ x4b, const float* __restrict__ ob,
                       const float* __restrict__ g, const float* __restrict__ bb,
                       const float* __restrict__ resw, const float4* __restrict__ xcur,
                       const float* __restrict__ in_w, const float* __restrict__ in_b,
                       const float* __restrict__ w1, const float* __restrict__ b1,
                       const float* __restrict__ w2, const float* __restrict__ b2,
                       float* __restrict__ out) {
    int tid = threadIdx.x;
    int node = (blockIdx.x * blockDim.x + tid) >> 6;
    int lane = tid & 63;
    if (node >= N_NODES) return;
    float4 zp = ((const float4*)sumexpP)[lane];
    bsum4(zp.x, zp.y, zp.z, zp.w);
    int hh = (lane & 15) >> 2;
    float z = (hh == 0) ? zp.x : (hh == 1) ? zp.y : (hh == 2) ? zp.z : zp.w;
    float a = 0.f;
    if (lane < 16) a = att16[node * 16 + lane] / z;
    a = dpp_addf<DPP_ROR4>(a);
    a = dpp_addf<DPP_ROR8>(a);
    float y0 = rdlane(a, 0), y1 = rdlane(a, 1), y2 = rdlane(a, 2), y3 = rdlane(a, 3);
    float4 x4v = x4b[node];
    y0 += ob[0] + x4v.x; y1 += ob[1] + x4v.y;
    y2 += ob[2] + x4v.z; y3 += ob[3] + x4v.w;
    float mu = 0.25f * (y0 + y1 + y2 + y3);
    float d0 = y0 - mu, d1 = y1 - mu, d2 = y2 - mu, d3 = y3 - mu;
    float var = 0.25f * (d0 * d0 + d1 * d1 + d2 * d2 + d3 * d3);
    float rs = rsqrtf(var + 1e-5f);
    float4 xold = xcur[node];
    float rw = resw[0];
    float n0 = d0 * rs * g[0] + bb[0] + xold.x * rw;
    float n1 = d1 * rs * g[1] + bb[1] + xold.y * rw;
    float n2 = d2 * rs * g[2] + bb[2] + xold.z * rw;
    float n3 = d3 * rs * g[3] + bb[3] + xold.w * rw;
    float hv = in_b[lane] + n0 * in_w[lane] + n1 * in_w[64 + lane]
             + n2 * in_w[128 + lane] + n3 * in_w[192 + lane];
    int j2 = lane & 31;
    float m = b1[j2];
    for (int k = 0; k < 64; k++) m += rdlane(hv, k) * w1[k * 32 + j2];
    m = fmaxf(m, 0.f);
    float4 w2v = ((const float4*)w2)[j2];
    float v0 = m * w2v.x, v1 = m * w2v.y, v2 = m * w2v.z, v3 = m * w2v.w;
    bsum4(v0, v1, v2, v3);  // each j2 counted twice (both halves) -> *0.5
    float o0 = tanhf(0.5f * v0 + b2[0]) * 0.3f;
    float o1 = tanhf(0.5f * v1 + b2[1]) * 0.3f;
    float o2 = tanhf(0.5f * v2 + b2[2]) * 0.3f;
    float o3 = tanhf(0.5f * v3 + b2[3]) * 0.3f;
    if (lane == 0) ((float4*)out)[node] = make_float4(o0, o1, o2, o3);
}

// ---------- launch ----------
extern "C" void kernel_launch(void* const* d_in, const int* in_sizes, int n_in,
                              void* d_out, int out_size, void* d_ws, size_t ws_size,
                              hipStream_t stream) {
    const float* x        = (const float*)d_in[0];
    const int*   ei       = (const int*)d_in[1];
    const float* ea       = (const float*)d_in[2];
    const float* in_w     = (const float*)d_in[3];
    const float* in_b     = (const float*)d_in[4];
    const float* conv_rw1 = (const float*)d_in[5];
    const float* conv_rb1 = (const float*)d_in[6];
    const float* conv_rw2 = (const float*)d_in[7];
    const float* conv_rb2 = (const float*)d_in[8];
    // d_in[9..12] (imag path) dead: x4 = h4[:, :4] only touches real[:, :4]
    const float* conv_sw  = (const float*)d_in[13];
    const float* conv_sb  = (const float*)d_in[14];
    const float* att_qw   = (const float*)d_in[15];
    const float* att_qb   = (const float*)d_in[16];
    const float* att_kw   = (const float*)d_in[17];
    const float* att_kb   = (const float*)d_in[18];
    const float* att_vw   = (const float*)d_in[19];
    const float* att_vb   = (const float*)d_in[20];
    const float* att_ow   = (const float*)d_in[21];
    const float* att_ob   = (const float*)d_in[22];
    const float* ln_g     = (const float*)d_in[23];
    const float* ln_b     = (const float*)d_in[24];
    const float* out_w1   = (const float*)d_in[25];
    const float* out_b1   = (const float*)d_in[26];
    const float* out_w2   = (const float*)d_in[27];
    const float* out_b2   = (const float*)d_in[28];
    const float* res_w    = (const float*)d_in[29];

    const int* row = ei;
    const int* col = ei + N_EDGES;

    char* ws = (char*)d_ws;
    size_t off = 0;
    auto alloc = [&](size_t bytes) -> void* {
        void* p = ws + off;
        off = (off + bytes + 255) & ~(size_t)255;
        return p;
    };
    unsigned* cntC     = (unsigned*)alloc(N_NODES * 4);
    uint2*    colEA    = (uint2*)alloc((size_t)N_NODES * BUCKET * 8);
    float*    att16    = (float*)alloc((size_t)N_NODES * 16 * 4);
    float4*   x4b      = (float4*)alloc((size_t)N_NODES * 16);
    float4*   xcur     = (float4*)alloc((size_t)N_NODES * 16);
    float*    cst      = (float*)alloc(4 * 128 * 4);
    float*    cstV     = (float*)alloc(4 * 128 * 4);
    float*    cstM     = (float*)alloc(4 * 384 * 4);  // per-layer Weff/beff/Sweff/sbe
    float*    sumexpP  = (float*)alloc(64 * 4 * 4);   // 64-way-split z partials

    dim3 b256(256);
    int grpBlocks   = (N_NODES + 15) / 16;      // 16 dsts per block (k23b, k5_att)
    int nodeBlocks4 = (N_NODES + 15) / 16;      // wave per 4 nodes (k61)

    hipMemsetAsync(cntC, 0, N_NODES * 4, stream);
    k_setup<<<8 * EDGE_TB + COPY_NB + 12, b256, 0, stream>>>(
        x, cntC, xcur, row, col, ea, colEA,
        att_qw, att_qb, att_kw, att_kb, att_vw, att_vb, att_ow,
        in_w, in_b, conv_rw1, conv_rb1, conv_sw,
        cst, cstV, cstM);

    for (int i = 0; i < 4; i++) {
        const float* rw1 = conv_rw1 + i * 66 * 64;
        const float* rw2 = conv_rw2 + i * 64 * 64;
        const float* rb2 = conv_rb2 + i * 64;
        const float* sbl = conv_sb + i * 256;

        if (i > 0) {
            k61<<<nodeBlocks4, b256, 0, stream>>>(att16, sumexpP, x4b,
                                                  att_ob + (i - 1) * 4, ln_g + (i - 1) * 4,
                                                  ln_b + (i - 1) * 4, res_w + (i - 1),
                                                  xcur);
        }
        k23b<<<grpBlocks, b256, 0, stream>>>(cntC, colEA, xcur, rw1, rw2,
                                             cstM + i * 384, rb2, sbl, x4b, sumexpP);
        k5_att<<<grpBlocks, b256, 0, stream>>>(cntC, colEA, x4b, cst + i * 128,
                                               cstV + i * 128, att16, sumexpP);
    }
    k6pred<<<(N_NODES + 3) / 4, b256, 0, stream>>>(att16, sumexpP, x4b, att_ob + 12, ln_g + 12,
                                            ln_b + 12, res_w + 3, xcur, in_w, in_b,
                                            out_w1, out_b1, out_w2, out_b2, (float*)d_out);
}